// Round 1
// baseline (589.970 us; speedup 1.0000x reference)
//
#include <hip/hip_runtime.h>
#include <hip/hip_bf16.h>

// ---------------------------------------------------------------------------
// Fused MHA forward, MI355X (gfx950).
// Pipeline: cvt(x,W*) -> bf16 ; GEMM q=(x@WQ)/8, k=x@WK, vT=(x@WV)^T ;
//           flash attention (causal + pad mask) -> concat bf16 ;
//           out = concat @ WO (fp32).
// Sizes: H=16, DM=1024, DK=DV=64, N=4, L=2048, M=N*L=8192.
// ---------------------------------------------------------------------------

typedef unsigned short ushort_t;
typedef __bf16 bf16x8 __attribute__((ext_vector_type(8)));
typedef float  f32x4  __attribute__((ext_vector_type(4)));
typedef unsigned short us4 __attribute__((ext_vector_type(4)));

#define HEADS 16
#define DM    1024
#define DK    64
#define NBAT  4
#define LSEQ  2048
#define MTOT  (NBAT*LSEQ)   // 8192

__device__ __forceinline__ ushort_t f2bf(float f) {
    union { float f; unsigned u; } a; a.f = f;
    unsigned r = a.u + 0x7fffu + ((a.u >> 16) & 1u);   // RNE
    return (ushort_t)(r >> 16);
}

__device__ __forceinline__ void gload16(const ushort_t* g, ushort_t* l) {
    __builtin_amdgcn_global_load_lds(
        (const __attribute__((address_space(1))) void*)g,
        (__attribute__((address_space(3))) void*)l, 16, 0, 0);
}

// --------------------------- converters ------------------------------------
__global__ __launch_bounds__(256) void cvt_f32_bf16(const float* __restrict__ in,
                                                    ushort_t* __restrict__ out, int n4) {
    int i = blockIdx.x * 256 + threadIdx.x;
    if (i >= n4) return;
    float4 v = reinterpret_cast<const float4*>(in)[i];
    us4 o;
    o[0] = f2bf(v.x); o[1] = f2bf(v.y); o[2] = f2bf(v.z); o[3] = f2bf(v.w);
    reinterpret_cast<us4*>(out)[i] = o;
}

// out[b][c][r] = in[b][r][c]   (bf16 transpose of each [R][C] slab)
__global__ __launch_bounds__(256) void cvt_transpose(const float* __restrict__ in,
                                                     ushort_t* __restrict__ out,
                                                     int R, int C, int total) {
    int i = blockIdx.x * 256 + threadIdx.x;
    if (i >= total) return;
    int rc = R * C;
    int b = i / rc; int rem = i - b * rc;
    int c = rem / R; int r = rem - c * R;
    out[i] = f2bf(in[(size_t)(b * R + r) * C + c]);
}

// --------------------------- GEMM (A[M][1024] @ BT[N'][1024]^T) -------------
// BM=128, BN=64, BK=64, 256 threads / 4 waves. Wave w: rows [w*32,w*32+32).
// MODE 0: bf16 out at Cout + by*524288 + m*64 + col, scaled   (q / k)
// MODE 1: bf16 out transposed vT[by][n][col][l]               (v)
// MODE 2: fp32 out at Cout[m*1024 + by*64 + col]              (final)
template<int MODE>
__global__ __launch_bounds__(256, 2)
void gemm_bt(const ushort_t* __restrict__ Ag, const ushort_t* __restrict__ BT,
             void* __restrict__ Cout, float scale) {
    const int bm = blockIdx.x, by = blockIdx.y;
    const int tid = threadIdx.x;
    const int w = tid >> 6, lane = tid & 63;
    const int g = lane >> 4, c = lane & 15;
    const int m0 = bm * 128;
    const ushort_t* Bbase = BT + (size_t)by * 65536;   // 64*1024

    __shared__ __align__(16) ushort_t As[128 * 64];    // 16 KB, swizzled
    __shared__ __align__(16) ushort_t Bs[64 * 64];     //  8 KB, swizzled

    f32x4 acc[2][4];
    #pragma unroll
    for (int i = 0; i < 2; ++i)
        #pragma unroll
        for (int j = 0; j < 4; ++j) acc[i][j] = (f32x4){0.f, 0.f, 0.f, 0.f};

    const int rsub = (w << 3) + (lane >> 3);   // 0..31
    const int s8   = lane & 7;

    for (int t = 0; t < 16; ++t) {
        const int k0 = t * 64;
        #pragma unroll
        for (int is = 0; is < 4; ++is) {
            const int row = is * 32 + rsub;
            gload16(Ag + (size_t)(m0 + row) * 1024 + k0 + ((s8 ^ (row & 7)) << 3),
                    &As[is * 2048 + w * 512]);
        }
        #pragma unroll
        for (int is = 0; is < 2; ++is) {
            const int row = is * 32 + rsub;
            gload16(Bbase + (size_t)row * 1024 + k0 + ((s8 ^ (row & 7)) << 3),
                    &Bs[is * 2048 + w * 512]);
        }
        __syncthreads();
        #pragma unroll
        for (int kk = 0; kk < 2; ++kk) {
            bf16x8 af[2], bfr[4];
            #pragma unroll
            for (int mf = 0; mf < 2; ++mf) {
                const int row = w * 32 + mf * 16 + c;
                const int slot = (kk * 4 + g) ^ (row & 7);
                af[mf] = *reinterpret_cast<const bf16x8*>(&As[row * 64 + slot * 8]);
            }
            #pragma unroll
            for (int nf = 0; nf < 4; ++nf) {
                const int row = nf * 16 + c;
                const int slot = (kk * 4 + g) ^ (row & 7);
                bfr[nf] = *reinterpret_cast<const bf16x8*>(&Bs[row * 64 + slot * 8]);
            }
            #pragma unroll
            for (int mf = 0; mf < 2; ++mf)
                #pragma unroll
                for (int nf = 0; nf < 4; ++nf)
                    acc[mf][nf] = __builtin_amdgcn_mfma_f32_16x16x32_bf16(
                        af[mf], bfr[nf], acc[mf][nf], 0, 0, 0);
        }
        __syncthreads();
    }

    #pragma unroll
    for (int mf = 0; mf < 2; ++mf) {
        const int mbase = m0 + w * 32 + mf * 16 + g * 4;
        #pragma unroll
        for (int nf = 0; nf < 4; ++nf) {
            const int col = nf * 16 + c;
            if (MODE == 0) {
                ushort_t* o = (ushort_t*)Cout + (size_t)by * 524288;
                #pragma unroll
                for (int r = 0; r < 4; ++r)
                    o[(size_t)(mbase + r) * 64 + col] = f2bf(acc[mf][nf][r] * scale);
            } else if (MODE == 1) {
                ushort_t* o = (ushort_t*)Cout + (size_t)by * 524288;
                us4 pk;
                #pragma unroll
                for (int r = 0; r < 4; ++r) pk[r] = f2bf(acc[mf][nf][r]);
                const int nIdx = mbase >> 11, l = mbase & 2047;
                *reinterpret_cast<us4*>(
                    &o[(size_t)nIdx * 131072 + (size_t)col * 2048 + l]) = pk;
            } else {
                float* o = (float*)Cout;
                #pragma unroll
                for (int r = 0; r < 4; ++r)
                    o[(size_t)(mbase + r) * 1024 + by * 64 + col] = acc[mf][nf][r];
            }
        }
    }
}

// --------------------------- flash attention --------------------------------
// grid (L/64, N, H), 256 thr / 4 indep waves; wave w owns q rows [w*16,w*16+16).
// q pre-scaled by 1/8. K,V(as vT) frags read directly from global (L2/L3-hot).
__global__ __launch_bounds__(256, 2)
void attn_kernel(const ushort_t* __restrict__ qb, const ushort_t* __restrict__ kb,
                 const ushort_t* __restrict__ vtb, const float* __restrict__ mi,
                 ushort_t* __restrict__ cat) {
    const int qblk = blockIdx.x, n = blockIdx.y, h = blockIdx.z;
    const int tid = threadIdx.x;
    const int w = tid >> 6, lane = tid & 63;
    const int g = lane >> 4, c = lane & 15;
    const int q0 = qblk * 64;

    const ushort_t* qhn = qb  + (size_t)h * 524288 + (size_t)n * 131072;  // [2048][64]
    const ushort_t* khn = kb  + (size_t)h * 524288 + (size_t)n * 131072;  // [2048][64]
    const ushort_t* vhn = vtb + (size_t)h * 524288 + (size_t)n * 131072;  // [64][2048]

    // Q fragments (2 k-steps of 32)
    bf16x8 qf[2];
    {
        const ushort_t* qp = qhn + (size_t)(q0 + w * 16 + c) * 64 + g * 8;
        qf[0] = *reinterpret_cast<const bf16x8*>(qp);
        qf[1] = *reinterpret_cast<const bf16x8*>(qp + 32);
    }
    float mq[4];
    #pragma unroll
    for (int r = 0; r < 4; ++r)
        mq[r] = mi[(size_t)n * 2048 + q0 + w * 16 + g * 4 + r];

    float mrun[4], lrun[4];
    f32x4 accO[4];
    #pragma unroll
    for (int r = 0; r < 4; ++r) { mrun[r] = -1e30f; lrun[r] = 0.f; }
    #pragma unroll
    for (int nf = 0; nf < 4; ++nf) accO[nf] = (f32x4){0.f, 0.f, 0.f, 0.f};

    __shared__ __align__(16) __bf16 sP[4 * 16 * 80];   // wave-private 16x80 (pad)
    __bf16* wp = &sP[w * 1280];

    const int jmax = qblk;
    for (int j = 0; j <= jmax; ++j) {
        const int kbase = j * 64;
        // ---- S = Q @ K^T  (per wave: 16 q-rows x 64 k-cols) ----
        f32x4 s[4];
        #pragma unroll
        for (int nf = 0; nf < 4; ++nf) s[nf] = (f32x4){0.f, 0.f, 0.f, 0.f};
        #pragma unroll
        for (int kk = 0; kk < 2; ++kk)
            #pragma unroll
            for (int nf = 0; nf < 4; ++nf) {
                const ushort_t* kp = khn + (size_t)(kbase + nf * 16 + c) * 64 + kk * 32 + g * 8;
                bf16x8 kf = *reinterpret_cast<const bf16x8*>(kp);
                s[nf] = __builtin_amdgcn_mfma_f32_16x16x32_bf16(qf[kk], kf, s[nf], 0, 0, 0);
            }
        // ---- mask (pad always, causal on diagonal tile) ----
        const bool diag = (j == jmax);
        float mkv[4];
        #pragma unroll
        for (int nf = 0; nf < 4; ++nf)
            mkv[nf] = mi[(size_t)n * 2048 + kbase + nf * 16 + c];
        #pragma unroll
        for (int nf = 0; nf < 4; ++nf)
            #pragma unroll
            for (int r = 0; r < 4; ++r) {
                const int kcol = kbase + nf * 16 + c;
                const int qrow = q0 + w * 16 + g * 4 + r;
                if ((mkv[nf] == 0.f) | (mq[r] == 0.f) | (diag && (kcol > qrow)))
                    s[nf][r] = -1e30f;
            }
        // ---- online softmax ----
        float mt[4];
        #pragma unroll
        for (int r = 0; r < 4; ++r)
            mt[r] = fmaxf(fmaxf(s[0][r], s[1][r]), fmaxf(s[2][r], s[3][r]));
        #pragma unroll
        for (int d = 1; d < 16; d <<= 1)
            #pragma unroll
            for (int r = 0; r < 4; ++r) mt[r] = fmaxf(mt[r], __shfl_xor(mt[r], d));
        float sc[4], rs[4];
        #pragma unroll
        for (int r = 0; r < 4; ++r) {
            const float mnew = fmaxf(mrun[r], mt[r]);
            sc[r] = __expf(mrun[r] - mnew);
            mrun[r] = mnew;
            rs[r] = 0.f;
        }
        #pragma unroll
        for (int nf = 0; nf < 4; ++nf)
            #pragma unroll
            for (int r = 0; r < 4; ++r) {
                const float p = __expf(s[nf][r] - mrun[r]);
                s[nf][r] = p;
                rs[r] += p;
            }
        #pragma unroll
        for (int d = 1; d < 16; d <<= 1)
            #pragma unroll
            for (int r = 0; r < 4; ++r) rs[r] += __shfl_xor(rs[r], d);
        #pragma unroll
        for (int r = 0; r < 4; ++r) lrun[r] = lrun[r] * sc[r] + rs[r];
        #pragma unroll
        for (int nf = 0; nf < 4; ++nf)
            #pragma unroll
            for (int r = 0; r < 4; ++r) accO[nf][r] *= sc[r];
        // ---- P -> LDS (bf16, transposed to a-frag layout) ----
        #pragma unroll
        for (int nf = 0; nf < 4; ++nf)
            #pragma unroll
            for (int r = 0; r < 4; ++r)
                wp[(g * 4 + r) * 80 + nf * 16 + c] = (__bf16)s[nf][r];
        // ---- O += P @ V ----
        #pragma unroll
        for (int kk = 0; kk < 2; ++kk) {
            bf16x8 pa = *reinterpret_cast<const bf16x8*>(&wp[c * 80 + kk * 32 + g * 8]);
            #pragma unroll
            for (int nf = 0; nf < 4; ++nf) {
                const ushort_t* vp = vhn + (size_t)(nf * 16 + c) * 2048 + kbase + kk * 32 + g * 8;
                bf16x8 vf = *reinterpret_cast<const bf16x8*>(vp);
                accO[nf] = __builtin_amdgcn_mfma_f32_16x16x32_bf16(pa, vf, accO[nf], 0, 0, 0);
            }
        }
    }
    // ---- epilogue: O/l -> concat[n][q][h*64+d] (bf16) ----
    #pragma unroll
    for (int r = 0; r < 4; ++r) {
        const float inv = (mrun[r] > -1e29f && lrun[r] > 0.f) ? (1.0f / lrun[r]) : 0.f;
        const int qrow = q0 + w * 16 + g * 4 + r;
        const size_t base = (size_t)(n * 2048 + qrow) * 1024 + h * 64;
        #pragma unroll
        for (int nf = 0; nf < 4; ++nf)
            cat[base + nf * 16 + c] = f2bf(accO[nf][r] * inv);
    }
}

// --------------------------- launcher ---------------------------------------
extern "C" void kernel_launch(void* const* d_in, const int* in_sizes, int n_in,
                              void* d_out, int out_size, void* d_ws, size_t ws_size,
                              hipStream_t stream) {
    const float* x  = (const float*)d_in[0];
    const float* mi = (const float*)d_in[1];
    const float* WQ = (const float*)d_in[2];
    const float* WK = (const float*)d_in[3];
    const float* WV = (const float*)d_in[4];
    const float* WO = (const float*)d_in[5];
    float* out = (float*)d_out;

    ushort_t* ws  = (ushort_t*)d_ws;
    ushort_t* xb  = ws;                    // 8192*1024           = 8388608
    ushort_t* wqt = xb  + 8388608;         // 16*64*1024          = 1048576
    ushort_t* wkt = wqt + 1048576;
    ushort_t* wvt = wkt + 1048576;
    ushort_t* wot = wvt + 1048576;         // 1024*1024           = 1048576
    ushort_t* qb  = wot + 1048576;         // [16][4][2048][64]   = 8388608
    ushort_t* kb  = qb  + 8388608;
    ushort_t* vtb = kb  + 8388608;         // [16][4][64][2048]
    ushort_t* cat = xb;                    // reuse xb after QKV GEMMs (16 MB)

    cvt_f32_bf16<<<8192, 256, 0, stream>>>(x, xb, 2097152);
    cvt_transpose<<<4096, 256, 0, stream>>>(WQ, wqt, 1024, 64, 1048576);
    cvt_transpose<<<4096, 256, 0, stream>>>(WK, wkt, 1024, 64, 1048576);
    cvt_transpose<<<4096, 256, 0, stream>>>(WV, wvt, 1024, 64, 1048576);
    cvt_transpose<<<4096, 256, 0, stream>>>(WO, wot, 1024, 1024, 1048576);

    dim3 g1(64, 16);
    gemm_bt<0><<<g1, 256, 0, stream>>>(xb, wqt, qb, 0.125f);   // q = (x WQ)/8
    gemm_bt<0><<<g1, 256, 0, stream>>>(xb, wkt, kb, 1.0f);     // k
    gemm_bt<1><<<g1, 256, 0, stream>>>(xb, wvt, vtb, 1.0f);    // vT

    dim3 g2(32, 4, 16);
    attn_kernel<<<g2, 256, 0, stream>>>(qb, kb, vtb, mi, cat);

    dim3 g3(64, 16);
    gemm_bt<2><<<g3, 256, 0, stream>>>(cat, wot, out, 1.0f);   // out fp32
}

// Round 2
// 347.337 us; speedup vs baseline: 1.6986x; 1.6986x over previous
//
#include <hip/hip_runtime.h>
#include <hip/hip_bf16.h>

// ---------------------------------------------------------------------------
// Fused MHA forward, MI355X (gfx950).
// Pipeline: cvt(x,W*) -> bf16 ; GEMM q=(x@WQ)/8, k=x@WK, vT=(x@WV)^T ;
//           flash attention (causal + pad mask, LDS-staged K/V) -> concat bf16;
//           out = concat @ WO (fp32).
// Sizes: H=16, DM=1024, DK=DV=64, N=4, L=2048, M=N*L=8192.
// ---------------------------------------------------------------------------

typedef unsigned short ushort_t;
typedef __bf16 bf16x8 __attribute__((ext_vector_type(8)));
typedef float  f32x4  __attribute__((ext_vector_type(4)));
typedef unsigned short us4 __attribute__((ext_vector_type(4)));

#define HEADS 16
#define DM    1024
#define DK    64
#define NBAT  4
#define LSEQ  2048
#define MTOT  (NBAT*LSEQ)   // 8192

__device__ __forceinline__ ushort_t f2bf(float f) {
    union { float f; unsigned u; } a; a.f = f;
    unsigned r = a.u + 0x7fffu + ((a.u >> 16) & 1u);   // RNE
    return (ushort_t)(r >> 16);
}

__device__ __forceinline__ void gload16(const ushort_t* g, ushort_t* l) {
    __builtin_amdgcn_global_load_lds(
        (const __attribute__((address_space(1))) void*)g,
        (__attribute__((address_space(3))) void*)l, 16, 0, 0);
}

// --------------------------- converters ------------------------------------
__global__ __launch_bounds__(256) void cvt_f32_bf16(const float* __restrict__ in,
                                                    ushort_t* __restrict__ out, int n4) {
    int i = blockIdx.x * 256 + threadIdx.x;
    if (i >= n4) return;
    float4 v = reinterpret_cast<const float4*>(in)[i];
    us4 o;
    o[0] = f2bf(v.x); o[1] = f2bf(v.y); o[2] = f2bf(v.z); o[3] = f2bf(v.w);
    reinterpret_cast<us4*>(out)[i] = o;
}

// out[b][c][r] = in[b][r][c]   (bf16 transpose of each [R][C] slab)
__global__ __launch_bounds__(256) void cvt_transpose(const float* __restrict__ in,
                                                     ushort_t* __restrict__ out,
                                                     int R, int C, int total) {
    int i = blockIdx.x * 256 + threadIdx.x;
    if (i >= total) return;
    int rc = R * C;
    int b = i / rc; int rem = i - b * rc;
    int c = rem / R; int r = rem - c * R;
    out[i] = f2bf(in[(size_t)(b * R + r) * C + c]);
}

// --------------------------- GEMM (A[M][1024] @ BT[N'][1024]^T) -------------
// BM=128, BN=64, BK=64, 256 threads / 4 waves. Wave w: rows [w*32,w*32+32).
// MODE 0: bf16 out at Cout + by*524288 + m*64 + col, scaled   (q / k)
// MODE 1: bf16 out transposed vT[by][n][col][l]               (v)
// MODE 2: fp32 out at Cout[m*1024 + by*64 + col]              (final)
template<int MODE>
__global__ __launch_bounds__(256, 2)
void gemm_bt(const ushort_t* __restrict__ Ag, const ushort_t* __restrict__ BT,
             void* __restrict__ Cout, float scale) {
    const int bm = blockIdx.x, by = blockIdx.y;
    const int tid = threadIdx.x;
    const int w = tid >> 6, lane = tid & 63;
    const int g = lane >> 4, c = lane & 15;
    const int m0 = bm * 128;
    const ushort_t* Bbase = BT + (size_t)by * 65536;   // 64*1024

    __shared__ __align__(16) ushort_t As[128 * 64];    // 16 KB, swizzled
    __shared__ __align__(16) ushort_t Bs[64 * 64];     //  8 KB, swizzled

    f32x4 acc[2][4];
    #pragma unroll
    for (int i = 0; i < 2; ++i)
        #pragma unroll
        for (int j = 0; j < 4; ++j) acc[i][j] = (f32x4){0.f, 0.f, 0.f, 0.f};

    const int rsub = (w << 3) + (lane >> 3);   // 0..31
    const int s8   = lane & 7;

    for (int t = 0; t < 16; ++t) {
        const int k0 = t * 64;
        #pragma unroll
        for (int is = 0; is < 4; ++is) {
            const int row = is * 32 + rsub;
            gload16(Ag + (size_t)(m0 + row) * 1024 + k0 + ((s8 ^ (row & 7)) << 3),
                    &As[is * 2048 + w * 512]);
        }
        #pragma unroll
        for (int is = 0; is < 2; ++is) {
            const int row = is * 32 + rsub;
            gload16(Bbase + (size_t)row * 1024 + k0 + ((s8 ^ (row & 7)) << 3),
                    &Bs[is * 2048 + w * 512]);
        }
        __syncthreads();
        #pragma unroll
        for (int kk = 0; kk < 2; ++kk) {
            bf16x8 af[2], bfr[4];
            #pragma unroll
            for (int mf = 0; mf < 2; ++mf) {
                const int row = w * 32 + mf * 16 + c;
                const int slot = (kk * 4 + g) ^ (row & 7);
                af[mf] = *reinterpret_cast<const bf16x8*>(&As[row * 64 + slot * 8]);
            }
            #pragma unroll
            for (int nf = 0; nf < 4; ++nf) {
                const int row = nf * 16 + c;
                const int slot = (kk * 4 + g) ^ (row & 7);
                bfr[nf] = *reinterpret_cast<const bf16x8*>(&Bs[row * 64 + slot * 8]);
            }
            #pragma unroll
            for (int mf = 0; mf < 2; ++mf)
                #pragma unroll
                for (int nf = 0; nf < 4; ++nf)
                    acc[mf][nf] = __builtin_amdgcn_mfma_f32_16x16x32_bf16(
                        af[mf], bfr[nf], acc[mf][nf], 0, 0, 0);
        }
        __syncthreads();
    }

    #pragma unroll
    for (int mf = 0; mf < 2; ++mf) {
        const int mbase = m0 + w * 32 + mf * 16 + g * 4;
        #pragma unroll
        for (int nf = 0; nf < 4; ++nf) {
            const int col = nf * 16 + c;
            if (MODE == 0) {
                ushort_t* o = (ushort_t*)Cout + (size_t)by * 524288;
                #pragma unroll
                for (int r = 0; r < 4; ++r)
                    o[(size_t)(mbase + r) * 64 + col] = f2bf(acc[mf][nf][r] * scale);
            } else if (MODE == 1) {
                ushort_t* o = (ushort_t*)Cout + (size_t)by * 524288;
                us4 pk;
                #pragma unroll
                for (int r = 0; r < 4; ++r) pk[r] = f2bf(acc[mf][nf][r]);
                const int nIdx = mbase >> 11, l = mbase & 2047;
                *reinterpret_cast<us4*>(
                    &o[(size_t)nIdx * 131072 + (size_t)col * 2048 + l]) = pk;
            } else {
                float* o = (float*)Cout;
                #pragma unroll
                for (int r = 0; r < 4; ++r)
                    o[(size_t)(mbase + r) * 1024 + by * 64 + col] = acc[mf][nf][r];
            }
        }
    }
}

// --------------------------- flash attention --------------------------------
// grid (L/64, N, H), 256 thr / 4 waves; wave w owns q rows [w*16,w*16+16).
// q pre-scaled by 1/8. K/V tiles staged in LDS (double-buffered,
// global_load_lds w=16, XOR-swizzled source + swizzled ds_read_b128).
__global__ __launch_bounds__(256, 2)
void attn_kernel(const ushort_t* __restrict__ qb, const ushort_t* __restrict__ kb,
                 const ushort_t* __restrict__ vtb, const float* __restrict__ mi,
                 ushort_t* __restrict__ cat) {
    const int qblk = gridDim.x - 1 - blockIdx.x;   // longest blocks dispatch first
    const int n = blockIdx.y, h = blockIdx.z;
    const int tid = threadIdx.x;
    const int w = tid >> 6, lane = tid & 63;
    const int g = lane >> 4, c = lane & 15;
    const int q0 = qblk * 64;

    const ushort_t* qhn = qb  + (size_t)h * 524288 + (size_t)n * 131072;  // [2048][64]
    const ushort_t* khn = kb  + (size_t)h * 524288 + (size_t)n * 131072;  // [2048][64]
    const ushort_t* vhn = vtb + (size_t)h * 524288 + (size_t)n * 131072;  // [64][2048]

    __shared__ __align__(16) ushort_t Ks[2][64 * 64];  // 16 KB, swizzled tiles
    __shared__ __align__(16) ushort_t Vs[2][64 * 64];  // 16 KB
    __shared__ __align__(16) __bf16 sP[4 * 16 * 80];   // 10 KB wave-private P

    const int rsub = (w << 3) + (lane >> 3);   // 0..31
    const int s8   = lane & 7;

    // stage K/V tile j into buffer b (async, 4 x gload16 per thread)
    auto stage = [&](int jb, int b) {
        const int kbase = jb * 64;
        #pragma unroll
        for (int is = 0; is < 2; ++is) {
            const int row = is * 32 + rsub;
            const int sg  = (s8 ^ (row & 7)) << 3;
            gload16(khn + (size_t)(kbase + row) * 64 + sg, &Ks[b][is * 2048 + w * 512]);
            gload16(vhn + (size_t)row * 2048 + kbase + sg, &Vs[b][is * 2048 + w * 512]);
        }
    };

    // Q fragments (2 k-steps of 32), q pre-scaled by 1/8
    bf16x8 qf[2];
    {
        const ushort_t* qp = qhn + (size_t)(q0 + w * 16 + c) * 64 + g * 8;
        qf[0] = *reinterpret_cast<const bf16x8*>(qp);
        qf[1] = *reinterpret_cast<const bf16x8*>(qp + 32);
    }
    float mq[4];
    #pragma unroll
    for (int r = 0; r < 4; ++r)
        mq[r] = mi[(size_t)n * 2048 + q0 + w * 16 + g * 4 + r];

    float mrun[4], lrun[4];
    f32x4 accO[4];
    #pragma unroll
    for (int r = 0; r < 4; ++r) { mrun[r] = -1e30f; lrun[r] = 0.f; }
    #pragma unroll
    for (int nf = 0; nf < 4; ++nf) accO[nf] = (f32x4){0.f, 0.f, 0.f, 0.f};

    __bf16* wp = &sP[w * 1280];

    const int jmax = qblk;
    stage(0, 0);
    __syncthreads();
    int buf = 0;

    for (int j = 0; j <= jmax; ++j) {
        const int kbase = j * 64;
        // ---- prefetch next tile into the other buffer ----
        if (j < jmax) stage(j + 1, buf ^ 1);
        // ---- pad-mask values for this tile's k-columns (L2-hot, issue early) --
        float mkv[4];
        #pragma unroll
        for (int nf = 0; nf < 4; ++nf)
            mkv[nf] = mi[(size_t)n * 2048 + kbase + nf * 16 + c];
        // ---- S = Q @ K^T  (per wave: 16 q-rows x 64 k-cols) ----
        f32x4 s[4];
        #pragma unroll
        for (int nf = 0; nf < 4; ++nf) s[nf] = (f32x4){0.f, 0.f, 0.f, 0.f};
        #pragma unroll
        for (int kk = 0; kk < 2; ++kk)
            #pragma unroll
            for (int nf = 0; nf < 4; ++nf) {
                const int row  = nf * 16 + c;
                const int slot = (kk * 4 + g) ^ (row & 7);
                bf16x8 kf = *reinterpret_cast<const bf16x8*>(&Ks[buf][row * 64 + slot * 8]);
                s[nf] = __builtin_amdgcn_mfma_f32_16x16x32_bf16(qf[kk], kf, s[nf], 0, 0, 0);
            }
        // ---- mask (pad always, causal on diagonal tile) ----
        const bool diag = (j == jmax);
        #pragma unroll
        for (int nf = 0; nf < 4; ++nf)
            #pragma unroll
            for (int r = 0; r < 4; ++r) {
                const int kcol = kbase + nf * 16 + c;
                const int qrow = q0 + w * 16 + g * 4 + r;
                if ((mkv[nf] == 0.f) | (mq[r] == 0.f) | (diag && (kcol > qrow)))
                    s[nf][r] = -1e30f;
            }
        // ---- online softmax ----
        float mt[4];
        #pragma unroll
        for (int r = 0; r < 4; ++r)
            mt[r] = fmaxf(fmaxf(s[0][r], s[1][r]), fmaxf(s[2][r], s[3][r]));
        #pragma unroll
        for (int d = 1; d < 16; d <<= 1)
            #pragma unroll
            for (int r = 0; r < 4; ++r) mt[r] = fmaxf(mt[r], __shfl_xor(mt[r], d));
        float sc[4], rs[4];
        #pragma unroll
        for (int r = 0; r < 4; ++r) {
            const float mnew = fmaxf(mrun[r], mt[r]);
            sc[r] = __expf(mrun[r] - mnew);
            mrun[r] = mnew;
            rs[r] = 0.f;
        }
        #pragma unroll
        for (int nf = 0; nf < 4; ++nf)
            #pragma unroll
            for (int r = 0; r < 4; ++r) {
                const float p = __expf(s[nf][r] - mrun[r]);
                s[nf][r] = p;
                rs[r] += p;
            }
        #pragma unroll
        for (int d = 1; d < 16; d <<= 1)
            #pragma unroll
            for (int r = 0; r < 4; ++r) rs[r] += __shfl_xor(rs[r], d);
        #pragma unroll
        for (int r = 0; r < 4; ++r) lrun[r] = lrun[r] * sc[r] + rs[r];
        #pragma unroll
        for (int nf = 0; nf < 4; ++nf)
            #pragma unroll
            for (int r = 0; r < 4; ++r) accO[nf][r] *= sc[r];
        // ---- P -> LDS (bf16, transposed to a-frag layout; wave-private) ----
        #pragma unroll
        for (int nf = 0; nf < 4; ++nf)
            #pragma unroll
            for (int r = 0; r < 4; ++r)
                wp[(g * 4 + r) * 80 + nf * 16 + c] = (__bf16)s[nf][r];
        // ---- O += P @ V  (V from swizzled LDS tile) ----
        #pragma unroll
        for (int kk = 0; kk < 2; ++kk) {
            bf16x8 pa = *reinterpret_cast<const bf16x8*>(&wp[c * 80 + kk * 32 + g * 8]);
            #pragma unroll
            for (int nf = 0; nf < 4; ++nf) {
                const int row  = nf * 16 + c;
                const int slot = (kk * 4 + g) ^ (row & 7);
                bf16x8 vf = *reinterpret_cast<const bf16x8*>(&Vs[buf][row * 64 + slot * 8]);
                accO[nf] = __builtin_amdgcn_mfma_f32_16x16x32_bf16(pa, vf, accO[nf], 0, 0, 0);
            }
        }
        // one barrier per iter: drains prefetch (vmcnt) + guards buffer reuse
        __syncthreads();
        buf ^= 1;
    }
    // ---- epilogue: O/l -> concat[n][q][h*64+d] (bf16) ----
    #pragma unroll
    for (int r = 0; r < 4; ++r) {
        const float inv = (mrun[r] > -1e29f && lrun[r] > 0.f) ? (1.0f / lrun[r]) : 0.f;
        const int qrow = q0 + w * 16 + g * 4 + r;
        const size_t base = (size_t)(n * 2048 + qrow) * 1024 + h * 64;
        #pragma unroll
        for (int nf = 0; nf < 4; ++nf)
            cat[base + nf * 16 + c] = f2bf(accO[nf][r] * inv);
    }
}

// --------------------------- launcher ---------------------------------------
extern "C" void kernel_launch(void* const* d_in, const int* in_sizes, int n_in,
                              void* d_out, int out_size, void* d_ws, size_t ws_size,
                              hipStream_t stream) {
    const float* x  = (const float*)d_in[0];
    const float* mi = (const float*)d_in[1];
    const float* WQ = (const float*)d_in[2];
    const float* WK = (const float*)d_in[3];
    const float* WV = (const float*)d_in[4];
    const float* WO = (const float*)d_in[5];
    float* out = (float*)d_out;

    ushort_t* ws  = (ushort_t*)d_ws;
    ushort_t* xb  = ws;                    // 8192*1024           = 8388608
    ushort_t* wqt = xb  + 8388608;         // 16*64*1024          = 1048576
    ushort_t* wkt = wqt + 1048576;
    ushort_t* wvt = wkt + 1048576;
    ushort_t* wot = wvt + 1048576;         // 1024*1024           = 1048576
    ushort_t* qb  = wot + 1048576;         // [16][4][2048][64]   = 8388608
    ushort_t* kb  = qb  + 8388608;
    ushort_t* vtb = kb  + 8388608;         // [16][4][64][2048]
    ushort_t* cat = xb;                    // reuse xb after QKV GEMMs (16 MB)

    cvt_f32_bf16<<<8192, 256, 0, stream>>>(x, xb, 2097152);
    cvt_transpose<<<4096, 256, 0, stream>>>(WQ, wqt, 1024, 64, 1048576);
    cvt_transpose<<<4096, 256, 0, stream>>>(WK, wkt, 1024, 64, 1048576);
    cvt_transpose<<<4096, 256, 0, stream>>>(WV, wvt, 1024, 64, 1048576);
    cvt_transpose<<<4096, 256, 0, stream>>>(WO, wot, 1024, 1024, 1048576);

    dim3 g1(64, 16);
    gemm_bt<0><<<g1, 256, 0, stream>>>(xb, wqt, qb, 0.125f);   // q = (x WQ)/8
    gemm_bt<0><<<g1, 256, 0, stream>>>(xb, wkt, kb, 1.0f);     // k
    gemm_bt<1><<<g1, 256, 0, stream>>>(xb, wvt, vtb, 1.0f);    // vT

    dim3 g2(32, 4, 16);
    attn_kernel<<<g2, 256, 0, stream>>>(qb, kb, vtb, mi, cat);

    dim3 g3(64, 16);
    gemm_bt<2><<<g3, 256, 0, stream>>>(cat, wot, out, 1.0f);   // out fp32
}

// Round 3
// 238.191 us; speedup vs baseline: 2.4769x; 1.4582x over previous
//
#include <hip/hip_runtime.h>
#include <hip/hip_bf16.h>

// ---------------------------------------------------------------------------
// Fused MHA forward, MI355X (gfx950).
// cvt(x,W*) -> bf16 ; GEMM q=(x@WQ)/8, k=x@WK, vT=(x@WV)^T ;
// flash attention (swapped-operand: S^T = K Q^T, O^T = V^T P^T, lane-local
// softmax, in-register P, paired q-tiles for causal balance) -> concat bf16 ;
// out = concat @ WO (fp32).
// Sizes: H=16, DM=1024, DK=DV=64, N=4, L=2048, M=N*L=8192.
// ---------------------------------------------------------------------------

typedef unsigned short ushort_t;
typedef __bf16 bf16x8 __attribute__((ext_vector_type(8)));
typedef float  f32x4  __attribute__((ext_vector_type(4)));
typedef unsigned short us4 __attribute__((ext_vector_type(4)));
typedef short s16x4 __attribute__((ext_vector_type(4)));

__device__ __forceinline__ ushort_t f2bf(float f) {
    union { float f; unsigned u; } a; a.f = f;
    unsigned r = a.u + 0x7fffu + ((a.u >> 16) & 1u);   // RNE
    return (ushort_t)(r >> 16);
}

__device__ __forceinline__ void gload16(const ushort_t* g, ushort_t* l) {
    __builtin_amdgcn_global_load_lds(
        (const __attribute__((address_space(1))) void*)g,
        (__attribute__((address_space(3))) void*)l, 16, 0, 0);
}

// --------------------------- converters ------------------------------------
__global__ __launch_bounds__(256) void cvt_f32_bf16(const float* __restrict__ in,
                                                    ushort_t* __restrict__ out, int n4) {
    int i = blockIdx.x * 256 + threadIdx.x;
    if (i >= n4) return;
    float4 v = reinterpret_cast<const float4*>(in)[i];
    us4 o;
    o[0] = f2bf(v.x); o[1] = f2bf(v.y); o[2] = f2bf(v.z); o[3] = f2bf(v.w);
    reinterpret_cast<us4*>(out)[i] = o;
}

// out[b][c][r] = in[b][r][c]   (bf16 transpose of each [R][C] slab)
__global__ __launch_bounds__(256) void cvt_transpose(const float* __restrict__ in,
                                                     ushort_t* __restrict__ out,
                                                     int R, int C, int total) {
    int i = blockIdx.x * 256 + threadIdx.x;
    if (i >= total) return;
    int rc = R * C;
    int b = i / rc; int rem = i - b * rc;
    int c = rem / R; int r = rem - c * R;
    out[i] = f2bf(in[(size_t)(b * R + r) * C + c]);
}

// --------------------------- GEMM (A[M][1024] @ BT[N'][1024]^T) -------------
// BM=128, BN=64, BK=64, 256 threads / 4 waves. Wave w: rows [w*32,w*32+32).
// MODE 0: bf16 out at Cout + by*524288 + m*64 + col, scaled   (q / k)
// MODE 1: bf16 out transposed vT[by][n][col][l]               (v)
// MODE 2: fp32 out at Cout[m*1024 + by*64 + col]              (final)
template<int MODE>
__global__ __launch_bounds__(256, 2)
void gemm_bt(const ushort_t* __restrict__ Ag, const ushort_t* __restrict__ BT,
             void* __restrict__ Cout, float scale) {
    const int bm = blockIdx.x, by = blockIdx.y;
    const int tid = threadIdx.x;
    const int w = tid >> 6, lane = tid & 63;
    const int g = lane >> 4, c = lane & 15;
    const int m0 = bm * 128;
    const ushort_t* Bbase = BT + (size_t)by * 65536;   // 64*1024

    __shared__ __align__(16) ushort_t As[128 * 64];    // 16 KB, swizzled
    __shared__ __align__(16) ushort_t Bs[64 * 64];     //  8 KB, swizzled

    f32x4 acc[2][4];
    #pragma unroll
    for (int i = 0; i < 2; ++i)
        #pragma unroll
        for (int j = 0; j < 4; ++j) acc[i][j] = (f32x4){0.f, 0.f, 0.f, 0.f};

    const int rsub = (w << 3) + (lane >> 3);   // 0..31
    const int s8   = lane & 7;

    for (int t = 0; t < 16; ++t) {
        const int k0 = t * 64;
        #pragma unroll
        for (int is = 0; is < 4; ++is) {
            const int row = is * 32 + rsub;
            gload16(Ag + (size_t)(m0 + row) * 1024 + k0 + ((s8 ^ (row & 7)) << 3),
                    &As[is * 2048 + w * 512]);
        }
        #pragma unroll
        for (int is = 0; is < 2; ++is) {
            const int row = is * 32 + rsub;
            gload16(Bbase + (size_t)row * 1024 + k0 + ((s8 ^ (row & 7)) << 3),
                    &Bs[is * 2048 + w * 512]);
        }
        __syncthreads();
        #pragma unroll
        for (int kk = 0; kk < 2; ++kk) {
            bf16x8 af[2], bfr[4];
            #pragma unroll
            for (int mf = 0; mf < 2; ++mf) {
                const int row = w * 32 + mf * 16 + c;
                const int slot = (kk * 4 + g) ^ (row & 7);
                af[mf] = *reinterpret_cast<const bf16x8*>(&As[row * 64 + slot * 8]);
            }
            #pragma unroll
            for (int nf = 0; nf < 4; ++nf) {
                const int row = nf * 16 + c;
                const int slot = (kk * 4 + g) ^ (row & 7);
                bfr[nf] = *reinterpret_cast<const bf16x8*>(&Bs[row * 64 + slot * 8]);
            }
            #pragma unroll
            for (int mf = 0; mf < 2; ++mf)
                #pragma unroll
                for (int nf = 0; nf < 4; ++nf)
                    acc[mf][nf] = __builtin_amdgcn_mfma_f32_16x16x32_bf16(
                        af[mf], bfr[nf], acc[mf][nf], 0, 0, 0);
        }
        __syncthreads();
    }

    #pragma unroll
    for (int mf = 0; mf < 2; ++mf) {
        const int mbase = m0 + w * 32 + mf * 16 + g * 4;
        #pragma unroll
        for (int nf = 0; nf < 4; ++nf) {
            const int col = nf * 16 + c;
            if (MODE == 0) {
                ushort_t* o = (ushort_t*)Cout + (size_t)by * 524288;
                #pragma unroll
                for (int r = 0; r < 4; ++r)
                    o[(size_t)(mbase + r) * 64 + col] = f2bf(acc[mf][nf][r] * scale);
            } else if (MODE == 1) {
                ushort_t* o = (ushort_t*)Cout + (size_t)by * 524288;
                us4 pk;
                #pragma unroll
                for (int r = 0; r < 4; ++r) pk[r] = f2bf(acc[mf][nf][r]);
                const int nIdx = mbase >> 11, l = mbase & 2047;
                *reinterpret_cast<us4*>(
                    &o[(size_t)nIdx * 131072 + (size_t)col * 2048 + l]) = pk;
            } else {
                float* o = (float*)Cout;
                #pragma unroll
                for (int r = 0; r < 4; ++r)
                    o[(size_t)(mbase + r) * 1024 + by * 64 + col] = acc[mf][nf][r];
            }
        }
    }
}

// --------------------------- flash attention --------------------------------
// grid (16, N, H), 256 thr / 4 waves. Block bx handles paired q-tiles
// {bx, 31-bx} (33 kv-iterations each -> perfectly balanced causal work).
// Wave w owns 16 q-rows per tile; qrow = q0 + (lane&15) is LANE-LOCAL.
// S^T = mfma(K,Q) so softmax reduction is 15 in-reg ops + 2 shuffles;
// P^T stays in registers and feeds O^T = mfma_16x16x16(V^T, P^T) directly.
__global__ __launch_bounds__(256, 4)
void attn_kernel(const ushort_t* __restrict__ qb, const ushort_t* __restrict__ kb,
                 const ushort_t* __restrict__ vtb, const float* __restrict__ mi,
                 ushort_t* __restrict__ cat) {
    const int bx = blockIdx.x;                    // 0..15
    const int n = blockIdx.y, h = blockIdx.z;
    const int tid = threadIdx.x;
    const int w = tid >> 6, lane = tid & 63;
    const int g = lane >> 4, c = lane & 15;
    const int qblkA = bx, qblkB = 31 - bx;        // (bx+1)+(32-bx) = 33 iters
    const int q0A = qblkA * 64 + w * 16;
    const int q0B = qblkB * 64 + w * 16;

    const ushort_t* qhn = qb  + (size_t)h * 524288 + (size_t)n * 131072;  // [2048][64]
    const ushort_t* khn = kb  + (size_t)h * 524288 + (size_t)n * 131072;  // [2048][64]
    const ushort_t* vhn = vtb + (size_t)h * 524288 + (size_t)n * 131072;  // [64][2048]
    const float*    mrow = mi + (size_t)n * 2048;

    __shared__ __align__(16) ushort_t Ks[2][64 * 64];  // 16 KB total (swizzled)
    __shared__ __align__(16) ushort_t Vs[2][64 * 64];  // 16 KB

    const int rsub = (w << 3) + (lane >> 3);   // 0..31
    const int s8   = lane & 7;

    auto stage = [&](int jb, int b) {
        const int kbase = jb * 64;
        #pragma unroll
        for (int is = 0; is < 2; ++is) {
            const int row = is * 32 + rsub;
            const int sg  = (s8 ^ (row & 7)) << 3;
            gload16(khn + (size_t)(kbase + row) * 64 + sg, &Ks[b][is * 2048 + w * 512]);
            gload16(vhn + (size_t)row * 2048 + kbase + sg, &Vs[b][is * 2048 + w * 512]);
        }
    };

    // Q B-frags (x32 QK^T): qf[kk] = Q[q0 + c][kk*32 + g*8 .. +7], pre-scaled 1/8
    bf16x8 qfA[2], qfB[2];
    {
        const ushort_t* qa = qhn + (size_t)(q0A + c) * 64 + g * 8;
        const ushort_t* qb2 = qhn + (size_t)(q0B + c) * 64 + g * 8;
        qfA[0] = *reinterpret_cast<const bf16x8*>(qa);
        qfA[1] = *reinterpret_cast<const bf16x8*>(qa + 32);
        qfB[0] = *reinterpret_cast<const bf16x8*>(qb2);
        qfB[1] = *reinterpret_cast<const bf16x8*>(qb2 + 32);
    }
    const float mqA = mrow[q0A + c];
    const float mqB = mrow[q0B + c];

    float mrunA = -1e30f, lrunA = 0.f, mrunB = -1e30f, lrunB = 0.f;
    f32x4 accA[4], accB[4];
    #pragma unroll
    for (int i = 0; i < 4; ++i) {
        accA[i] = (f32x4){0.f, 0.f, 0.f, 0.f};
        accB[i] = (f32x4){0.f, 0.f, 0.f, 0.f};
    }

    stage(0, 0);
    __syncthreads();
    int buf = 0;

    for (int j = 0; j <= qblkB; ++j) {
        if (j < qblkB) stage(j + 1, buf ^ 1);
        const int kbase = j * 64;
        float4 mkv[4];
        #pragma unroll
        for (int nf = 0; nf < 4; ++nf)
            mkv[nf] = *reinterpret_cast<const float4*>(&mrow[kbase + nf * 16 + g * 4]);

        auto do_pass = [&](const bf16x8* qf, f32x4* acc, float& mrun, float& lrun,
                           float mq, int q0, bool diag) {
            // ---- S^T = K @ Q^T : 8 x mfma 16x16x32 ----
            f32x4 s[4];
            #pragma unroll
            for (int nf = 0; nf < 4; ++nf) s[nf] = (f32x4){0.f, 0.f, 0.f, 0.f};
            #pragma unroll
            for (int kk = 0; kk < 2; ++kk)
                #pragma unroll
                for (int nf = 0; nf < 4; ++nf) {
                    const int row  = nf * 16 + c;
                    const int byte = row * 128 + (((kk * 4 + g) ^ (c & 7)) << 4);
                    bf16x8 kf = *reinterpret_cast<const bf16x8*>(
                        reinterpret_cast<const char*>(&Ks[buf][0]) + byte);
                    s[nf] = __builtin_amdgcn_mfma_f32_16x16x32_bf16(
                        kf, qf[kk], s[nf], 0, 0, 0);
                }
            // ---- mask: s[nf][r] is S[qrow=q0+c][kcol=kbase+nf*16+g*4+r] ----
            const int qrow = q0 + c;
            #pragma unroll
            for (int nf = 0; nf < 4; ++nf) {
                const float* mk = reinterpret_cast<const float*>(&mkv[nf]);
                #pragma unroll
                for (int r = 0; r < 4; ++r) {
                    const int kcol = kbase + nf * 16 + g * 4 + r;
                    if ((mk[r] == 0.f) | (mq == 0.f) | (diag && (kcol > qrow)))
                        s[nf][r] = -1e30f;
                }
            }
            // ---- lane-local online softmax ----
            float m01[4], m23[4];
            #pragma unroll
            for (int r = 0; r < 4; ++r) {
                m01[r] = fmaxf(s[0][r], s[1][r]);
                m23[r] = fmaxf(s[2][r], s[3][r]);
            }
            float mt = fmaxf(fmaxf(fmaxf(m01[0], m01[1]), fmaxf(m01[2], m01[3])),
                             fmaxf(fmaxf(m23[0], m23[1]), fmaxf(m23[2], m23[3])));
            mt = fmaxf(mt, __shfl_xor(mt, 16));
            mt = fmaxf(mt, __shfl_xor(mt, 32));
            const float mnew = fmaxf(mrun, mt);
            const float sc = __expf(mrun - mnew);
            float rs = 0.f;
            s16x4 pb[4];
            #pragma unroll
            for (int nf = 0; nf < 4; ++nf)
                #pragma unroll
                for (int r = 0; r < 4; ++r) {
                    const float p = __expf(s[nf][r] - mnew);
                    rs += p;
                    pb[nf][r] = (short)f2bf(p);
                }
            rs += __shfl_xor(rs, 16);
            rs += __shfl_xor(rs, 32);
            mrun = mnew;
            lrun = lrun * sc + rs;
            #pragma unroll
            for (int nfd = 0; nfd < 4; ++nfd)
                #pragma unroll
                for (int r = 0; r < 4; ++r) acc[nfd][r] *= sc;
            // ---- O^T += V^T @ P^T : 16 x mfma 16x16x16 (P in registers) ----
            #pragma unroll
            for (int kk = 0; kk < 4; ++kk)
                #pragma unroll
                for (int nfd = 0; nfd < 4; ++nfd) {
                    const int row   = nfd * 16 + c;
                    const int chunk = (kk * 2 + (g >> 1)) ^ (c & 7);
                    const int byte  = row * 128 + (chunk << 4) + (g & 1) * 8;
                    s16x4 vf = *reinterpret_cast<const s16x4*>(
                        reinterpret_cast<const char*>(&Vs[buf][0]) + byte);
                    acc[nfd] = __builtin_amdgcn_mfma_f32_16x16x16bf16_1k(
                        vf, pb[kk], acc[nfd], 0, 0, 0);
                }
        };

        if (j <= qblkA) do_pass(qfA, accA, mrunA, lrunA, mqA, q0A, j == qblkA);
        do_pass(qfB, accB, mrunB, lrunB, mqB, q0B, j == qblkB);

        __syncthreads();
        buf ^= 1;
    }

    // ---- epilogue: O^T[d][q] -> concat[n][q][h*64+d] (bf16) ----
    auto epi = [&](const f32x4* acc, float mrun, float lrun, int q0) {
        const float inv = (mrun > -1e29f && lrun > 0.f) ? (1.0f / lrun) : 0.f;
        const size_t base = (size_t)(n * 2048 + q0 + c) * 1024 + h * 64;
        #pragma unroll
        for (int nfd = 0; nfd < 4; ++nfd) {
            us4 pk;
            #pragma unroll
            for (int r = 0; r < 4; ++r) pk[r] = f2bf(acc[nfd][r] * inv);
            *reinterpret_cast<us4*>(&cat[base + nfd * 16 + g * 4]) = pk;
        }
    };
    epi(accA, mrunA, lrunA, q0A);
    epi(accB, mrunB, lrunB, q0B);
}

// --------------------------- launcher ---------------------------------------
extern "C" void kernel_launch(void* const* d_in, const int* in_sizes, int n_in,
                              void* d_out, int out_size, void* d_ws, size_t ws_size,
                              hipStream_t stream) {
    const float* x  = (const float*)d_in[0];
    const float* mi = (const float*)d_in[1];
    const float* WQ = (const float*)d_in[2];
    const float* WK = (const float*)d_in[3];
    const float* WV = (const float*)d_in[4];
    const float* WO = (const float*)d_in[5];
    float* out = (float*)d_out;

    ushort_t* ws  = (ushort_t*)d_ws;
    ushort_t* xb  = ws;                    // 8192*1024           = 8388608
    ushort_t* wqt = xb  + 8388608;         // 16*64*1024          = 1048576
    ushort_t* wkt = wqt + 1048576;
    ushort_t* wvt = wkt + 1048576;
    ushort_t* wot = wvt + 1048576;         // 1024*1024           = 1048576
    ushort_t* qb  = wot + 1048576;         // [16][4][2048][64]   = 8388608
    ushort_t* kb  = qb  + 8388608;
    ushort_t* vtb = kb  + 8388608;         // [16][4][64][2048]
    ushort_t* cat = xb;                    // reuse xb after QKV GEMMs (16 MB)

    cvt_f32_bf16<<<8192, 256, 0, stream>>>(x, xb, 2097152);
    cvt_transpose<<<4096, 256, 0, stream>>>(WQ, wqt, 1024, 64, 1048576);
    cvt_transpose<<<4096, 256, 0, stream>>>(WK, wkt, 1024, 64, 1048576);
    cvt_transpose<<<4096, 256, 0, stream>>>(WV, wvt, 1024, 64, 1048576);
    cvt_transpose<<<4096, 256, 0, stream>>>(WO, wot, 1024, 1024, 1048576);

    dim3 g1(64, 16);
    gemm_bt<0><<<g1, 256, 0, stream>>>(xb, wqt, qb, 0.125f);   // q = (x WQ)/8
    gemm_bt<0><<<g1, 256, 0, stream>>>(xb, wkt, kb, 1.0f);     // k
    gemm_bt<1><<<g1, 256, 0, stream>>>(xb, wvt, vtb, 1.0f);    // vT

    dim3 g2(16, 4, 16);
    attn_kernel<<<g2, 256, 0, stream>>>(qb, kb, vtb, mi, cat);

    dim3 g3(64, 16);
    gemm_bt<2><<<g3, 256, 0, stream>>>(cat, wot, out, 1.0f);   // out fp32
}

// Round 4
// 214.868 us; speedup vs baseline: 2.7457x; 1.1085x over previous
//
#include <hip/hip_runtime.h>
#include <hip/hip_bf16.h>

// ---------------------------------------------------------------------------
// Fused MHA forward, MI355X (gfx950).
// cvt(x,W*) -> bf16 ; fused GEMM {q=(x@WQ)*0.125*log2e, k=x@WK, vT=(x@WV)^T} ;
// flash attention (swapped-operand S^T=K Q^T, O^T=V^T P^T, lane-local exp2
// softmax, defer-max, cvt_pk bf16 pack, in-register P, paired q-tiles) ;
// out = concat @ WO (fp32).
// Sizes: H=16, DM=1024, DK=DV=64, N=4, L=2048, M=N*L=8192.
// ---------------------------------------------------------------------------

typedef unsigned short ushort_t;
typedef __bf16 bf16x8 __attribute__((ext_vector_type(8)));
typedef float  f32x4  __attribute__((ext_vector_type(4)));
typedef unsigned short us4 __attribute__((ext_vector_type(4)));
typedef short s16x4 __attribute__((ext_vector_type(4)));

__device__ __forceinline__ ushort_t f2bf(float f) {
    union { float f; unsigned u; } a; a.f = f;
    unsigned r = a.u + 0x7fffu + ((a.u >> 16) & 1u);   // RNE
    return (ushort_t)(r >> 16);
}

__device__ __forceinline__ void gload16(const ushort_t* g, ushort_t* l) {
    __builtin_amdgcn_global_load_lds(
        (const __attribute__((address_space(1))) void*)g,
        (__attribute__((address_space(3))) void*)l, 16, 0, 0);
}

// --------------------------- converters ------------------------------------
__global__ __launch_bounds__(256) void cvt_f32_bf16(const float* __restrict__ in,
                                                    ushort_t* __restrict__ out, int n4) {
    int i = blockIdx.x * 256 + threadIdx.x;
    if (i >= n4) return;
    float4 v = reinterpret_cast<const float4*>(in)[i];
    us4 o;
    o[0] = f2bf(v.x); o[1] = f2bf(v.y); o[2] = f2bf(v.z); o[3] = f2bf(v.w);
    reinterpret_cast<us4*>(out)[i] = o;
}

// out[b][c][r] = in[b][r][c]   (bf16 transpose of each [R][C] slab)
__global__ __launch_bounds__(256) void cvt_transpose(const float* __restrict__ in,
                                                     ushort_t* __restrict__ out,
                                                     int R, int C, int total) {
    int i = blockIdx.x * 256 + threadIdx.x;
    if (i >= total) return;
    int rc = R * C;
    int b = i / rc; int rem = i - b * rc;
    int c = rem / R; int r = rem - c * R;
    out[i] = f2bf(in[(size_t)(b * R + r) * C + c]);
}

// --------------------------- GEMM (A[M][1024] @ BT[N'][1024]^T) -------------
// BM=128, BN=64, BK=64, 256 threads / 4 waves. Wave w: rows [w*32,w*32+32).
// MODE 3: fused QKV. by<32 -> row-major bf16 out (scale for by<16: q);
//         by>=32   -> transposed vT store. Out base = Cout + by*524288.
// MODE 2: fp32 out at Cout[m*1024 + by*64 + col]              (final)
template<int MODE>
__global__ __launch_bounds__(256, 2)
void gemm_bt(const ushort_t* __restrict__ Ag, const ushort_t* __restrict__ BT,
             void* __restrict__ Cout, float scale) {
    const int bm = blockIdx.x, by = blockIdx.y;
    const int tid = threadIdx.x;
    const int w = tid >> 6, lane = tid & 63;
    const int g = lane >> 4, c = lane & 15;
    const int m0 = bm * 128;
    const ushort_t* Bbase = BT + (size_t)by * 65536;   // 64*1024

    __shared__ __align__(16) ushort_t As[128 * 64];    // 16 KB, swizzled
    __shared__ __align__(16) ushort_t Bs[64 * 64];     //  8 KB, swizzled

    f32x4 acc[2][4];
    #pragma unroll
    for (int i = 0; i < 2; ++i)
        #pragma unroll
        for (int j = 0; j < 4; ++j) acc[i][j] = (f32x4){0.f, 0.f, 0.f, 0.f};

    const int rsub = (w << 3) + (lane >> 3);   // 0..31
    const int s8   = lane & 7;

    for (int t = 0; t < 16; ++t) {
        const int k0 = t * 64;
        #pragma unroll
        for (int is = 0; is < 4; ++is) {
            const int row = is * 32 + rsub;
            gload16(Ag + (size_t)(m0 + row) * 1024 + k0 + ((s8 ^ (row & 7)) << 3),
                    &As[is * 2048 + w * 512]);
        }
        #pragma unroll
        for (int is = 0; is < 2; ++is) {
            const int row = is * 32 + rsub;
            gload16(Bbase + (size_t)row * 1024 + k0 + ((s8 ^ (row & 7)) << 3),
                    &Bs[is * 2048 + w * 512]);
        }
        __syncthreads();
        #pragma unroll
        for (int kk = 0; kk < 2; ++kk) {
            bf16x8 af[2], bfr[4];
            #pragma unroll
            for (int mf = 0; mf < 2; ++mf) {
                const int row = w * 32 + mf * 16 + c;
                const int slot = (kk * 4 + g) ^ (row & 7);
                af[mf] = *reinterpret_cast<const bf16x8*>(&As[row * 64 + slot * 8]);
            }
            #pragma unroll
            for (int nf = 0; nf < 4; ++nf) {
                const int row = nf * 16 + c;
                const int slot = (kk * 4 + g) ^ (row & 7);
                bfr[nf] = *reinterpret_cast<const bf16x8*>(&Bs[row * 64 + slot * 8]);
            }
            __builtin_amdgcn_s_setprio(1);
            #pragma unroll
            for (int mf = 0; mf < 2; ++mf)
                #pragma unroll
                for (int nf = 0; nf < 4; ++nf)
                    acc[mf][nf] = __builtin_amdgcn_mfma_f32_16x16x32_bf16(
                        af[mf], bfr[nf], acc[mf][nf], 0, 0, 0);
            __builtin_amdgcn_s_setprio(0);
        }
        __syncthreads();
    }

    #pragma unroll
    for (int mf = 0; mf < 2; ++mf) {
        const int mbase = m0 + w * 32 + mf * 16 + g * 4;
        #pragma unroll
        for (int nf = 0; nf < 4; ++nf) {
            const int col = nf * 16 + c;
            if (MODE == 3) {
                ushort_t* o = (ushort_t*)Cout + (size_t)by * 524288;
                if (by < 32) {
                    const float scl = (by < 16) ? scale : 1.0f;
                    #pragma unroll
                    for (int r = 0; r < 4; ++r)
                        o[(size_t)(mbase + r) * 64 + col] = f2bf(acc[mf][nf][r] * scl);
                } else {
                    us4 pk;
                    #pragma unroll
                    for (int r = 0; r < 4; ++r) pk[r] = f2bf(acc[mf][nf][r]);
                    const int nIdx = mbase >> 11, l = mbase & 2047;
                    *reinterpret_cast<us4*>(
                        &o[(size_t)nIdx * 131072 + (size_t)col * 2048 + l]) = pk;
                }
            } else {
                float* o = (float*)Cout;
                #pragma unroll
                for (int r = 0; r < 4; ++r)
                    o[(size_t)(mbase + r) * 1024 + by * 64 + col] = acc[mf][nf][r];
            }
        }
    }
}

// --------------------------- flash attention --------------------------------
// grid (16, N, H), 256 thr / 4 waves. Block bx handles paired q-tiles
// {bx, 31-bx} (33 kv-iterations each -> balanced causal work).
// qrow = q0 + (lane&15) is lane-local; softmax in exp2 domain (q pre-scaled
// by 0.125*log2e); defer-max THR=8; P packed via v_cvt_pk_bf16_f32.
__global__ __launch_bounds__(256, 4)
void attn_kernel(const ushort_t* __restrict__ qb, const ushort_t* __restrict__ kb,
                 const ushort_t* __restrict__ vtb, const float* __restrict__ mi,
                 ushort_t* __restrict__ cat) {
    const int bx = blockIdx.x;                    // 0..15
    const int n = blockIdx.y, h = blockIdx.z;
    const int tid = threadIdx.x;
    const int w = tid >> 6, lane = tid & 63;
    const int g = lane >> 4, c = lane & 15;
    const int qblkA = bx, qblkB = 31 - bx;        // (bx+1)+(32-bx) = 33 iters
    const int q0A = qblkA * 64 + w * 16;
    const int q0B = qblkB * 64 + w * 16;

    const ushort_t* qhn = qb  + (size_t)h * 524288 + (size_t)n * 131072;  // [2048][64]
    const ushort_t* khn = kb  + (size_t)h * 524288 + (size_t)n * 131072;  // [2048][64]
    const ushort_t* vhn = vtb + (size_t)h * 524288 + (size_t)n * 131072;  // [64][2048]
    const float*    mrow = mi + (size_t)n * 2048;

    __shared__ __align__(16) ushort_t Ks[2][64 * 64];  // 16 KB total (swizzled)
    __shared__ __align__(16) ushort_t Vs[2][64 * 64];  // 16 KB

    const int rsub = (w << 3) + (lane >> 3);   // 0..31
    const int s8   = lane & 7;

    auto stage = [&](int jb, int b) {
        const int kbase = jb * 64;
        #pragma unroll
        for (int is = 0; is < 2; ++is) {
            const int row = is * 32 + rsub;
            const int sg  = (s8 ^ (row & 7)) << 3;
            gload16(khn + (size_t)(kbase + row) * 64 + sg, &Ks[b][is * 2048 + w * 512]);
            gload16(vhn + (size_t)row * 2048 + kbase + sg, &Vs[b][is * 2048 + w * 512]);
        }
    };

    // Q B-frags (x32 QK^T): qf[kk] = Q[q0 + c][kk*32 + g*8 .. +7]
    bf16x8 qfA[2], qfB[2];
    {
        const ushort_t* qa = qhn + (size_t)(q0A + c) * 64 + g * 8;
        const ushort_t* qb2 = qhn + (size_t)(q0B + c) * 64 + g * 8;
        qfA[0] = *reinterpret_cast<const bf16x8*>(qa);
        qfA[1] = *reinterpret_cast<const bf16x8*>(qa + 32);
        qfB[0] = *reinterpret_cast<const bf16x8*>(qb2);
        qfB[1] = *reinterpret_cast<const bf16x8*>(qb2 + 32);
    }
    const float mqA = mrow[q0A + c];
    const float mqB = mrow[q0B + c];

    float mrunA = -1e30f, lrunA = 0.f, mrunB = -1e30f, lrunB = 0.f;
    f32x4 accA[4], accB[4];
    #pragma unroll
    for (int i = 0; i < 4; ++i) {
        accA[i] = (f32x4){0.f, 0.f, 0.f, 0.f};
        accB[i] = (f32x4){0.f, 0.f, 0.f, 0.f};
    }

    stage(0, 0);
    __syncthreads();
    int buf = 0;

    for (int j = 0; j <= qblkB; ++j) {
        if (j < qblkB) stage(j + 1, buf ^ 1);
        const int kbase = j * 64;
        // per-tile additive pad-mask bias, shared by both passes
        f32x4 bias[4];
        #pragma unroll
        for (int nf = 0; nf < 4; ++nf) {
            float4 mk = *reinterpret_cast<const float4*>(&mrow[kbase + nf * 16 + g * 4]);
            bias[nf][0] = (mk.x == 0.f) ? -1e30f : 0.f;
            bias[nf][1] = (mk.y == 0.f) ? -1e30f : 0.f;
            bias[nf][2] = (mk.z == 0.f) ? -1e30f : 0.f;
            bias[nf][3] = (mk.w == 0.f) ? -1e30f : 0.f;
        }

        auto do_pass = [&](const bf16x8* qf, f32x4* acc, float& mrun, float& lrun,
                           int q0, bool diag) {
            // ---- S^T = K @ Q^T : 8 x mfma 16x16x32 (exp2 domain) ----
            f32x4 s[4];
            #pragma unroll
            for (int nf = 0; nf < 4; ++nf) s[nf] = (f32x4){0.f, 0.f, 0.f, 0.f};
            __builtin_amdgcn_s_setprio(1);
            #pragma unroll
            for (int kk = 0; kk < 2; ++kk)
                #pragma unroll
                for (int nf = 0; nf < 4; ++nf) {
                    const int row  = nf * 16 + c;
                    const int byte = row * 128 + (((kk * 4 + g) ^ (c & 7)) << 4);
                    bf16x8 kf = *reinterpret_cast<const bf16x8*>(
                        reinterpret_cast<const char*>(&Ks[buf][0]) + byte);
                    s[nf] = __builtin_amdgcn_mfma_f32_16x16x32_bf16(
                        kf, qf[kk], s[nf], 0, 0, 0);
                }
            __builtin_amdgcn_s_setprio(0);
            // ---- mask: pad bias (per tile) + causal (diag tile only) ----
            #pragma unroll
            for (int nf = 0; nf < 4; ++nf) s[nf] += bias[nf];
            if (diag) {
                const int qrow = q0 + c;
                #pragma unroll
                for (int nf = 0; nf < 4; ++nf)
                    #pragma unroll
                    for (int r = 0; r < 4; ++r)
                        if (kbase + nf * 16 + g * 4 + r > qrow) s[nf][r] = -1e30f;
            }
            // ---- lane-local online softmax (exp2 domain, defer-max) ----
            float m01[4], m23[4];
            #pragma unroll
            for (int r = 0; r < 4; ++r) {
                m01[r] = fmaxf(s[0][r], s[1][r]);
                m23[r] = fmaxf(s[2][r], s[3][r]);
            }
            float mt = fmaxf(fmaxf(fmaxf(m01[0], m01[1]), fmaxf(m01[2], m01[3])),
                             fmaxf(fmaxf(m23[0], m23[1]), fmaxf(m23[2], m23[3])));
            mt = fmaxf(mt, __shfl_xor(mt, 16));
            mt = fmaxf(mt, __shfl_xor(mt, 32));
            if (!__all(mt - mrun <= 8.0f)) {
                const float mnew = fmaxf(mrun, mt);
                const float sc = __builtin_amdgcn_exp2f(mrun - mnew);
                #pragma unroll
                for (int nfd = 0; nfd < 4; ++nfd)
                    #pragma unroll
                    for (int r = 0; r < 4; ++r) acc[nfd][r] *= sc;
                lrun *= sc;
                mrun = mnew;
            }
            float rs = 0.f;
            union { unsigned u[2]; s16x4 v; } pb[4];
            #pragma unroll
            for (int nf = 0; nf < 4; ++nf) {
                const float p0 = __builtin_amdgcn_exp2f(s[nf][0] - mrun);
                const float p1 = __builtin_amdgcn_exp2f(s[nf][1] - mrun);
                const float p2 = __builtin_amdgcn_exp2f(s[nf][2] - mrun);
                const float p3 = __builtin_amdgcn_exp2f(s[nf][3] - mrun);
                rs += (p0 + p1) + (p2 + p3);
                asm("v_cvt_pk_bf16_f32 %0, %1, %2" : "=v"(pb[nf].u[0]) : "v"(p0), "v"(p1));
                asm("v_cvt_pk_bf16_f32 %0, %1, %2" : "=v"(pb[nf].u[1]) : "v"(p2), "v"(p3));
            }
            rs += __shfl_xor(rs, 16);
            rs += __shfl_xor(rs, 32);
            lrun += rs;
            // ---- O^T += V^T @ P^T : 16 x mfma 16x16x16 (P in registers) ----
            __builtin_amdgcn_s_setprio(1);
            #pragma unroll
            for (int kk = 0; kk < 4; ++kk)
                #pragma unroll
                for (int nfd = 0; nfd < 4; ++nfd) {
                    const int row   = nfd * 16 + c;
                    const int chunk = (kk * 2 + (g >> 1)) ^ (c & 7);
                    const int byte  = row * 128 + (chunk << 4) + (g & 1) * 8;
                    s16x4 vf = *reinterpret_cast<const s16x4*>(
                        reinterpret_cast<const char*>(&Vs[buf][0]) + byte);
                    acc[nfd] = __builtin_amdgcn_mfma_f32_16x16x16bf16_1k(
                        vf, pb[kk].v, acc[nfd], 0, 0, 0);
                }
            __builtin_amdgcn_s_setprio(0);
        };

        if (j <= qblkA) do_pass(qfA, accA, mrunA, lrunA, q0A, j == qblkA);
        do_pass(qfB, accB, mrunB, lrunB, q0B, j == qblkB);

        __syncthreads();
        buf ^= 1;
    }

    // ---- epilogue: O^T[d][q] -> concat[n][q][h*64+d] (bf16) ----
    auto epi = [&](const f32x4* acc, float mrun, float lrun, float mq, int q0) {
        const float inv = (mq != 0.f && mrun > -1e29f && lrun > 0.f)
                              ? (1.0f / lrun) : 0.f;
        const size_t base = (size_t)(n * 2048 + q0 + c) * 1024 + h * 64;
        #pragma unroll
        for (int nfd = 0; nfd < 4; ++nfd) {
            us4 pk;
            #pragma unroll
            for (int r = 0; r < 4; ++r) pk[r] = f2bf(acc[nfd][r] * inv);
            *reinterpret_cast<us4*>(&cat[base + nfd * 16 + g * 4]) = pk;
        }
    };
    epi(accA, mrunA, lrunA, mqA, q0A);
    epi(accB, mrunB, lrunB, mqB, q0B);
}

// --------------------------- launcher ---------------------------------------
extern "C" void kernel_launch(void* const* d_in, const int* in_sizes, int n_in,
                              void* d_out, int out_size, void* d_ws, size_t ws_size,
                              hipStream_t stream) {
    const float* x  = (const float*)d_in[0];
    const float* mi = (const float*)d_in[1];
    const float* WQ = (const float*)d_in[2];
    const float* WK = (const float*)d_in[3];
    const float* WV = (const float*)d_in[4];
    const float* WO = (const float*)d_in[5];
    float* out = (float*)d_out;

    ushort_t* ws  = (ushort_t*)d_ws;
    ushort_t* xb  = ws;                    // 8192*1024           = 8388608
    ushort_t* wqt = xb  + 8388608;         // 16*64*1024          = 1048576
    ushort_t* wkt = wqt + 1048576;         // (wqt/wkt/wvt contiguous: fused GEMM)
    ushort_t* wvt = wkt + 1048576;
    ushort_t* wot = wvt + 1048576;         // 1024*1024           = 1048576
    ushort_t* qb  = wot + 1048576;         // [16][4][2048][64]   = 8388608
    ushort_t* kb  = qb  + 8388608;         // (qb/kb/vtb contiguous: fused GEMM)
    ushort_t* vtb = kb  + 8388608;         // [16][4][64][2048]
    ushort_t* cat = xb;                    // reuse xb after QKV GEMM (16 MB)

    cvt_f32_bf16<<<8192, 256, 0, stream>>>(x, xb, 2097152);
    cvt_transpose<<<4096, 256, 0, stream>>>(WQ, wqt, 1024, 64, 1048576);
    cvt_transpose<<<4096, 256, 0, stream>>>(WK, wkt, 1024, 64, 1048576);
    cvt_transpose<<<4096, 256, 0, stream>>>(WV, wvt, 1024, 64, 1048576);
    cvt_transpose<<<4096, 256, 0, stream>>>(WO, wot, 1024, 1024, 1048576);

    // fused QKV: by 0-15 q (scaled 0.125*log2e), 16-31 k, 32-47 vT
    dim3 g1(64, 48);
    gemm_bt<3><<<g1, 256, 0, stream>>>(xb, wqt, qb, 0.18033688f);

    dim3 g2(16, 4, 16);
    attn_kernel<<<g2, 256, 0, stream>>>(qb, kb, vtb, mi, cat);

    dim3 g3(64, 16);
    gemm_bt<2><<<g3, 256, 0, stream>>>(cat, wot, out, 1.0f);   // out fp32
}

// Round 5
// 193.147 us; speedup vs baseline: 3.0545x; 1.1125x over previous
//
#include <hip/hip_runtime.h>
#include <hip/hip_bf16.h>

// ---------------------------------------------------------------------------
// Fused MHA forward, MI355X (gfx950).
// cvt(x) -> bf16 ; LDS-tiled transposed cvt of W* ;
// fused GEMM {q=(x@WQ)*0.125*log2e, k=x@WK, vT=(x@WV)^T} (BM=128,BN=128) ;
// flash attention (swapped-operand S^T=K Q^T, O^T=V^T P^T, lane-local exp2
// softmax, defer-max, cvt_pk bf16 pack, in-register P, paired q-tiles) ;
// out = concat @ WO (fp32, BN=128).
// Sizes: H=16, DM=1024, DK=DV=64, N=4, L=2048, M=N*L=8192.
// ---------------------------------------------------------------------------

typedef unsigned short ushort_t;
typedef __bf16 bf16x8 __attribute__((ext_vector_type(8)));
typedef float  f32x4  __attribute__((ext_vector_type(4)));
typedef unsigned short us4 __attribute__((ext_vector_type(4)));
typedef short s16x4 __attribute__((ext_vector_type(4)));

__device__ __forceinline__ ushort_t f2bf(float f) {
    union { float f; unsigned u; } a; a.f = f;
    unsigned r = a.u + 0x7fffu + ((a.u >> 16) & 1u);   // RNE
    return (ushort_t)(r >> 16);
}

__device__ __forceinline__ void gload16(const ushort_t* g, ushort_t* l) {
    __builtin_amdgcn_global_load_lds(
        (const __attribute__((address_space(1))) void*)g,
        (__attribute__((address_space(3))) void*)l, 16, 0, 0);
}

// --------------------------- converters ------------------------------------
__global__ __launch_bounds__(256) void cvt_f32_bf16(const float* __restrict__ in,
                                                    ushort_t* __restrict__ out, int n4) {
    int i = blockIdx.x * 256 + threadIdx.x;
    if (i >= n4) return;
    float4 v = reinterpret_cast<const float4*>(in)[i];
    us4 o;
    o[0] = f2bf(v.x); o[1] = f2bf(v.y); o[2] = f2bf(v.z); o[3] = f2bf(v.w);
    reinterpret_cast<us4*>(out)[i] = o;
}

// out[b][c][r] = in[b][r][c], 32x32 LDS tile, both sides coalesced.
// grid (C/32, R/32, B), 256 threads.
__global__ __launch_bounds__(256) void cvt_transpose32(const float* __restrict__ in,
                                                       ushort_t* __restrict__ out,
                                                       int R, int C) {
    const int b = blockIdx.z;
    const int c0 = blockIdx.x * 32, r0 = blockIdx.y * 32;
    const int tx = threadIdx.x & 31, ty = threadIdx.x >> 5;   // 8 rows/pass
    __shared__ ushort_t t[32][33];
    const float* ip = in + ((size_t)b * R + r0) * C + c0;
    #pragma unroll
    for (int i = 0; i < 4; ++i)
        t[ty + 8 * i][tx] = f2bf(ip[(size_t)(ty + 8 * i) * C + tx]);
    __syncthreads();
    ushort_t* op = out + ((size_t)b * C + c0) * R + r0;
    #pragma unroll
    for (int i = 0; i < 4; ++i)
        op[(size_t)(ty + 8 * i) * R + tx] = t[tx][ty + 8 * i];
}

// --------------------------- GEMM (A[M][1024] @ BT[N'][1024]^T) -------------
// BM=128, BN=128, BK=64, 256 threads / 4 waves (2x2), 4x4 frags per wave.
// MODE 3: fused QKV. Per-fragment slab s = 2*by + (col>>6):
//         s<16 -> q (bf16, scaled); s<32 -> k (bf16); s>=32 -> vT store.
// MODE 2: fp32 out at Cout[m*1024 + by*128 + col]             (final)
template<int MODE>
__global__ __launch_bounds__(256, 2)
void gemm_bt(const ushort_t* __restrict__ Ag, const ushort_t* __restrict__ BT,
             void* __restrict__ Cout, float scale) {
    const int bm = blockIdx.x, by = blockIdx.y;
    const int tid = threadIdx.x;
    const int w = tid >> 6, lane = tid & 63;
    const int wr = w >> 1, wc = w & 1;
    const int g = lane >> 4, c = lane & 15;
    const int m0 = bm * 128;
    const ushort_t* Bbase = BT + (size_t)by * 131072;   // 128*1024

    __shared__ __align__(16) ushort_t As[128 * 64];    // 16 KB, swizzled
    __shared__ __align__(16) ushort_t Bs[128 * 64];    // 16 KB, swizzled

    f32x4 acc[4][4];
    #pragma unroll
    for (int i = 0; i < 4; ++i)
        #pragma unroll
        for (int j = 0; j < 4; ++j) acc[i][j] = (f32x4){0.f, 0.f, 0.f, 0.f};

    const int rsub = (w << 3) + (lane >> 3);   // 0..31
    const int s8   = lane & 7;

    for (int t = 0; t < 16; ++t) {
        const int k0 = t * 64;
        #pragma unroll
        for (int is = 0; is < 4; ++is) {
            const int row = is * 32 + rsub;
            const int sg  = (s8 ^ (row & 7)) << 3;
            gload16(Ag + (size_t)(m0 + row) * 1024 + k0 + sg, &As[is * 2048 + w * 512]);
            gload16(Bbase + (size_t)row * 1024 + k0 + sg,     &Bs[is * 2048 + w * 512]);
        }
        __syncthreads();
        #pragma unroll
        for (int kk = 0; kk < 2; ++kk) {
            bf16x8 af[4], bfr[4];
            #pragma unroll
            for (int mf = 0; mf < 4; ++mf) {
                const int row = wr * 64 + mf * 16 + c;
                const int slot = (kk * 4 + g) ^ (row & 7);
                af[mf] = *reinterpret_cast<const bf16x8*>(&As[row * 64 + slot * 8]);
            }
            #pragma unroll
            for (int nf = 0; nf < 4; ++nf) {
                const int row = wc * 64 + nf * 16 + c;
                const int slot = (kk * 4 + g) ^ (row & 7);
                bfr[nf] = *reinterpret_cast<const bf16x8*>(&Bs[row * 64 + slot * 8]);
            }
            __builtin_amdgcn_s_setprio(1);
            #pragma unroll
            for (int mf = 0; mf < 4; ++mf)
                #pragma unroll
                for (int nf = 0; nf < 4; ++nf)
                    acc[mf][nf] = __builtin_amdgcn_mfma_f32_16x16x32_bf16(
                        af[mf], bfr[nf], acc[mf][nf], 0, 0, 0);
            __builtin_amdgcn_s_setprio(0);
        }
        __syncthreads();
    }

    #pragma unroll
    for (int mf = 0; mf < 4; ++mf) {
        const int mbase = m0 + wr * 64 + mf * 16 + g * 4;
        #pragma unroll
        for (int nf = 0; nf < 4; ++nf) {
            const int colG = wc * 64 + nf * 16 + c;
            if (MODE == 3) {
                const int s  = by * 2 + (colG >> 6);
                const int c2 = colG & 63;
                ushort_t* o = (ushort_t*)Cout + (size_t)s * 524288;
                if (s < 32) {
                    const float scl = (s < 16) ? scale : 1.0f;
                    #pragma unroll
                    for (int r = 0; r < 4; ++r)
                        o[(size_t)(mbase + r) * 64 + c2] = f2bf(acc[mf][nf][r] * scl);
                } else {
                    us4 pk;
                    #pragma unroll
                    for (int r = 0; r < 4; ++r) pk[r] = f2bf(acc[mf][nf][r]);
                    const int nIdx = mbase >> 11, l = mbase & 2047;
                    *reinterpret_cast<us4*>(
                        &o[(size_t)nIdx * 131072 + (size_t)c2 * 2048 + l]) = pk;
                }
            } else {
                float* o = (float*)Cout;
                #pragma unroll
                for (int r = 0; r < 4; ++r)
                    o[(size_t)(mbase + r) * 1024 + by * 128 + colG] = acc[mf][nf][r];
            }
        }
    }
}

// --------------------------- flash attention --------------------------------
// grid (16, N, H), 256 thr / 4 waves. Block bx handles paired q-tiles
// {bx, 31-bx} (33 kv-iterations each -> balanced causal work).
// qrow = q0 + (lane&15) is lane-local; softmax in exp2 domain (q pre-scaled
// by 0.125*log2e); defer-max THR=8; P packed via v_cvt_pk_bf16_f32.
__global__ __launch_bounds__(256, 4)
void attn_kernel(const ushort_t* __restrict__ qb, const ushort_t* __restrict__ kb,
                 const ushort_t* __restrict__ vtb, const float* __restrict__ mi,
                 ushort_t* __restrict__ cat) {
    const int bx = blockIdx.x;                    // 0..15
    const int n = blockIdx.y, h = blockIdx.z;
    const int tid = threadIdx.x;
    const int w = tid >> 6, lane = tid & 63;
    const int g = lane >> 4, c = lane & 15;
    const int qblkA = bx, qblkB = 31 - bx;        // (bx+1)+(32-bx) = 33 iters
    const int q0A = qblkA * 64 + w * 16;
    const int q0B = qblkB * 64 + w * 16;

    const ushort_t* qhn = qb  + (size_t)h * 524288 + (size_t)n * 131072;  // [2048][64]
    const ushort_t* khn = kb  + (size_t)h * 524288 + (size_t)n * 131072;  // [2048][64]
    const ushort_t* vhn = vtb + (size_t)h * 524288 + (size_t)n * 131072;  // [64][2048]
    const float*    mrow = mi + (size_t)n * 2048;

    __shared__ __align__(16) ushort_t Ks[2][64 * 64];  // 16 KB total (swizzled)
    __shared__ __align__(16) ushort_t Vs[2][64 * 64];  // 16 KB

    const int rsub = (w << 3) + (lane >> 3);   // 0..31
    const int s8   = lane & 7;

    auto stage = [&](int jb, int b) {
        const int kbase = jb * 64;
        #pragma unroll
        for (int is = 0; is < 2; ++is) {
            const int row = is * 32 + rsub;
            const int sg  = (s8 ^ (row & 7)) << 3;
            gload16(khn + (size_t)(kbase + row) * 64 + sg, &Ks[b][is * 2048 + w * 512]);
            gload16(vhn + (size_t)row * 2048 + kbase + sg, &Vs[b][is * 2048 + w * 512]);
        }
    };

    // Q B-frags (x32 QK^T): qf[kk] = Q[q0 + c][kk*32 + g*8 .. +7]
    bf16x8 qfA[2], qfB[2];
    {
        const ushort_t* qa = qhn + (size_t)(q0A + c) * 64 + g * 8;
        const ushort_t* qb2 = qhn + (size_t)(q0B + c) * 64 + g * 8;
        qfA[0] = *reinterpret_cast<const bf16x8*>(qa);
        qfA[1] = *reinterpret_cast<const bf16x8*>(qa + 32);
        qfB[0] = *reinterpret_cast<const bf16x8*>(qb2);
        qfB[1] = *reinterpret_cast<const bf16x8*>(qb2 + 32);
    }
    const float mqA = mrow[q0A + c];
    const float mqB = mrow[q0B + c];

    float mrunA = -1e30f, lrunA = 0.f, mrunB = -1e30f, lrunB = 0.f;
    f32x4 accA[4], accB[4];
    #pragma unroll
    for (int i = 0; i < 4; ++i) {
        accA[i] = (f32x4){0.f, 0.f, 0.f, 0.f};
        accB[i] = (f32x4){0.f, 0.f, 0.f, 0.f};
    }

    stage(0, 0);
    __syncthreads();
    int buf = 0;

    for (int j = 0; j <= qblkB; ++j) {
        if (j < qblkB) stage(j + 1, buf ^ 1);
        const int kbase = j * 64;
        // per-tile additive pad-mask bias, shared by both passes
        f32x4 bias[4];
        #pragma unroll
        for (int nf = 0; nf < 4; ++nf) {
            float4 mk = *reinterpret_cast<const float4*>(&mrow[kbase + nf * 16 + g * 4]);
            bias[nf][0] = (mk.x == 0.f) ? -1e30f : 0.f;
            bias[nf][1] = (mk.y == 0.f) ? -1e30f : 0.f;
            bias[nf][2] = (mk.z == 0.f) ? -1e30f : 0.f;
            bias[nf][3] = (mk.w == 0.f) ? -1e30f : 0.f;
        }

        auto do_pass = [&](const bf16x8* qf, f32x4* acc, float& mrun, float& lrun,
                           int q0, bool diag) {
            // ---- S^T = K @ Q^T : 8 x mfma 16x16x32 (exp2 domain) ----
            f32x4 s[4];
            #pragma unroll
            for (int nf = 0; nf < 4; ++nf) s[nf] = (f32x4){0.f, 0.f, 0.f, 0.f};
            __builtin_amdgcn_s_setprio(1);
            #pragma unroll
            for (int kk = 0; kk < 2; ++kk)
                #pragma unroll
                for (int nf = 0; nf < 4; ++nf) {
                    const int row  = nf * 16 + c;
                    const int byte = row * 128 + (((kk * 4 + g) ^ (c & 7)) << 4);
                    bf16x8 kf = *reinterpret_cast<const bf16x8*>(
                        reinterpret_cast<const char*>(&Ks[buf][0]) + byte);
                    s[nf] = __builtin_amdgcn_mfma_f32_16x16x32_bf16(
                        kf, qf[kk], s[nf], 0, 0, 0);
                }
            __builtin_amdgcn_s_setprio(0);
            // ---- mask: pad bias (per tile) + causal (diag tile only) ----
            #pragma unroll
            for (int nf = 0; nf < 4; ++nf) s[nf] += bias[nf];
            if (diag) {
                const int qrow = q0 + c;
                #pragma unroll
                for (int nf = 0; nf < 4; ++nf)
                    #pragma unroll
                    for (int r = 0; r < 4; ++r)
                        if (kbase + nf * 16 + g * 4 + r > qrow) s[nf][r] = -1e30f;
            }
            // ---- lane-local online softmax (exp2 domain, defer-max) ----
            float m01[4], m23[4];
            #pragma unroll
            for (int r = 0; r < 4; ++r) {
                m01[r] = fmaxf(s[0][r], s[1][r]);
                m23[r] = fmaxf(s[2][r], s[3][r]);
            }
            float mt = fmaxf(fmaxf(fmaxf(m01[0], m01[1]), fmaxf(m01[2], m01[3])),
                             fmaxf(fmaxf(m23[0], m23[1]), fmaxf(m23[2], m23[3])));
            mt = fmaxf(mt, __shfl_xor(mt, 16));
            mt = fmaxf(mt, __shfl_xor(mt, 32));
            if (!__all(mt - mrun <= 8.0f)) {
                const float mnew = fmaxf(mrun, mt);
                const float sc = __builtin_amdgcn_exp2f(mrun - mnew);
                #pragma unroll
                for (int nfd = 0; nfd < 4; ++nfd)
                    #pragma unroll
                    for (int r = 0; r < 4; ++r) acc[nfd][r] *= sc;
                lrun *= sc;
                mrun = mnew;
            }
            float rs = 0.f;
            union { unsigned u[2]; s16x4 v; } pb[4];
            #pragma unroll
            for (int nf = 0; nf < 4; ++nf) {
                const float p0 = __builtin_amdgcn_exp2f(s[nf][0] - mrun);
                const float p1 = __builtin_amdgcn_exp2f(s[nf][1] - mrun);
                const float p2 = __builtin_amdgcn_exp2f(s[nf][2] - mrun);
                const float p3 = __builtin_amdgcn_exp2f(s[nf][3] - mrun);
                rs += (p0 + p1) + (p2 + p3);
                asm("v_cvt_pk_bf16_f32 %0, %1, %2" : "=v"(pb[nf].u[0]) : "v"(p0), "v"(p1));
                asm("v_cvt_pk_bf16_f32 %0, %1, %2" : "=v"(pb[nf].u[1]) : "v"(p2), "v"(p3));
            }
            rs += __shfl_xor(rs, 16);
            rs += __shfl_xor(rs, 32);
            lrun += rs;
            // ---- O^T += V^T @ P^T : 16 x mfma 16x16x16 (P in registers) ----
            __builtin_amdgcn_s_setprio(1);
            #pragma unroll
            for (int kk = 0; kk < 4; ++kk)
                #pragma unroll
                for (int nfd = 0; nfd < 4; ++nfd) {
                    const int row   = nfd * 16 + c;
                    const int chunk = (kk * 2 + (g >> 1)) ^ (c & 7);
                    const int byte  = row * 128 + (chunk << 4) + (g & 1) * 8;
                    s16x4 vf = *reinterpret_cast<const s16x4*>(
                        reinterpret_cast<const char*>(&Vs[buf][0]) + byte);
                    acc[nfd] = __builtin_amdgcn_mfma_f32_16x16x16bf16_1k(
                        vf, pb[kk].v, acc[nfd], 0, 0, 0);
                }
            __builtin_amdgcn_s_setprio(0);
        };

        if (j <= qblkA) do_pass(qfA, accA, mrunA, lrunA, q0A, j == qblkA);
        do_pass(qfB, accB, mrunB, lrunB, q0B, j == qblkB);

        __syncthreads();
        buf ^= 1;
    }

    // ---- epilogue: O^T[d][q] -> concat[n][q][h*64+d] (bf16) ----
    auto epi = [&](const f32x4* acc, float mrun, float lrun, float mq, int q0) {
        const float inv = (mq != 0.f && mrun > -1e29f && lrun > 0.f)
                              ? (1.0f / lrun) : 0.f;
        const size_t base = (size_t)(n * 2048 + q0 + c) * 1024 + h * 64;
        #pragma unroll
        for (int nfd = 0; nfd < 4; ++nfd) {
            us4 pk;
            #pragma unroll
            for (int r = 0; r < 4; ++r) pk[r] = f2bf(acc[nfd][r] * inv);
            *reinterpret_cast<us4*>(&cat[base + nfd * 16 + g * 4]) = pk;
        }
    };
    epi(accA, mrunA, lrunA, mqA, q0A);
    epi(accB, mrunB, lrunB, mqB, q0B);
}

// --------------------------- launcher ---------------------------------------
extern "C" void kernel_launch(void* const* d_in, const int* in_sizes, int n_in,
                              void* d_out, int out_size, void* d_ws, size_t ws_size,
                              hipStream_t stream) {
    const float* x  = (const float*)d_in[0];
    const float* mi = (const float*)d_in[1];
    const float* WQ = (const float*)d_in[2];
    const float* WK = (const float*)d_in[3];
    const float* WV = (const float*)d_in[4];
    const float* WO = (const float*)d_in[5];
    float* out = (float*)d_out;

    ushort_t* ws  = (ushort_t*)d_ws;
    ushort_t* xb  = ws;                    // 8192*1024           = 8388608
    ushort_t* wqt = xb  + 8388608;         // 16*64*1024          = 1048576
    ushort_t* wkt = wqt + 1048576;         // (wqt/wkt/wvt contiguous: fused GEMM)
    ushort_t* wvt = wkt + 1048576;
    ushort_t* wot = wvt + 1048576;         // 1024*1024           = 1048576
    ushort_t* qb  = wot + 1048576;         // [16][4][2048][64]   = 8388608
    ushort_t* kb  = qb  + 8388608;         // (qb/kb/vtb contiguous: fused GEMM)
    ushort_t* vtb = kb  + 8388608;         // [16][4][64][2048]
    ushort_t* cat = xb;                    // reuse xb after QKV GEMM (16 MB)

    cvt_f32_bf16<<<8192, 256, 0, stream>>>(x, xb, 2097152);
    {
        dim3 gt(2, 32, 16);                // C/32, R/32, slabs
        cvt_transpose32<<<gt, 256, 0, stream>>>(WQ, wqt, 1024, 64);
        cvt_transpose32<<<gt, 256, 0, stream>>>(WK, wkt, 1024, 64);
        cvt_transpose32<<<gt, 256, 0, stream>>>(WV, wvt, 1024, 64);
        dim3 go(32, 32, 1);
        cvt_transpose32<<<go, 256, 0, stream>>>(WO, wot, 1024, 1024);
    }

    // fused QKV: slabs 0-15 q (scaled 0.125*log2e), 16-31 k, 32-47 vT
    dim3 g1(64, 24);
    gemm_bt<3><<<g1, 256, 0, stream>>>(xb, wqt, qb, 0.18033688f);

    dim3 g2(16, 4, 16);
    attn_kernel<<<g2, 256, 0, stream>>>(qb, kb, vtb, mi, cat);

    dim3 g3(64, 8);
    gemm_bt<2><<<g3, 256, 0, stream>>>(cat, wot, out, 1.0f);   // out fp32
}